// Round 10
// baseline (320.623 us; speedup 1.0000x reference)
//
#include <hip/hip_runtime.h>

typedef unsigned int u32;
typedef unsigned long long u64;

#define BB 4
#define NN 261888
#define KSEL 6000
#define CAP 8192
#define PC 1000
#define NMS_THR 0.7f
#define NW 94          /* ceil(KSEL/64) */
#define NR (NW*64)     /* padded mask rows = 6016 */
#define COLSPLIT 6     /* k_iou column-range split for occupancy */

#define HB 31                    /* hist blocks per batch */
#define CHUNK_H (NN/HB)          /* 8448 = 33*256 */
#define HITER (CHUNK_H/256)      /* 33 */
#define CB 93                    /* compact blocks per batch */
#define CHUNK_C (NN/CB)          /* 2816 = 11*256 */
#define CITER (CHUNK_C/256)      /* 11 */

// ---------------- ws layout (u32 units) ----------------
// hist1: BB*2048 | hist2: BB*2048 | sel: BB*4 | candCount: BB*32 (128B-padded) |
// cand(u64): BB*CAP | sorted(u64): BB*KSEL | boxes(f32): BB*KSEL*4 |
// mask(u64): BB*NW*NR  (COLUMN-MAJOR: mask[b][word][row])
#define HIST1_OFF 0
#define HIST2_OFF (BB*2048)
#define SEL_OFF   (BB*2048*2)
#define CNT_OFF   (BB*2048*2 + BB*4)
#define ZERO_WORDS (BB*2048*2 + BB*4 + BB*32)

__global__ void k_zero(u32* ws) {
    int i = blockIdx.x * 256 + threadIdx.x;
    if (i < ZERO_WORDS) ws[i] = 0u;
}

__global__ void k_hist1(const float2* __restrict__ probs2, u32* __restrict__ hist1) {
    __shared__ u32 lh[2048];
    int b = blockIdx.y;
    size_t base = (size_t)b * NN + (size_t)blockIdx.x * CHUNK_H;
    for (int j = threadIdx.x; j < 2048; j += 256) lh[j] = 0u;
    __syncthreads();
    #pragma unroll 4
    for (int it = 0; it < HITER; ++it) {
        float2 p = probs2[base + it * 256 + threadIdx.x];
        atomicAdd(&lh[__float_as_uint(p.y) >> 21], 1u);
    }
    __syncthreads();
    for (int j = threadIdx.x; j < 2048; j += 256) {
        u32 c = lh[j];
        if (c) atomicAdd(&hist1[b * 2048 + j], c);
    }
}

// descending-group scan: thread t owns bins 2047-8t .. 2047-8t-7
__global__ void k_sel1(const u32* __restrict__ hist1, u32* __restrict__ sel) {
    __shared__ u32 gsum[256];
    __shared__ u32 lh[2048];    // lh[k] = hist[2047-k]
    int b = blockIdx.x;
    int t = threadIdx.x;
    u32 s = 0;
    #pragma unroll
    for (int j = 0; j < 8; ++j) {
        u32 v = hist1[b * 2048 + 2047 - (t * 8 + j)];
        lh[t * 8 + j] = v;
        s += v;
    }
    gsum[t] = s;
    __syncthreads();
    if (t == 0) {
        u32 cum = 0;
        for (int g = 0; g < 256; ++g) {
            if (cum + gsum[g] >= (u32)KSEL) {
                for (int j = 0; j < 8; ++j) {
                    u32 c = lh[g * 8 + j];
                    if (cum + c >= (u32)KSEL) {
                        sel[b * 4 + 0] = (u32)(2047 - (g * 8 + j));
                        sel[b * 4 + 1] = cum;
                        break;
                    }
                    cum += c;
                }
                break;
            }
            cum += gsum[g];
        }
    }
}

__global__ void k_hist2(const float2* __restrict__ probs2, const u32* __restrict__ sel,
                        u32* __restrict__ hist2) {
    int b = blockIdx.y;
    u32 b1 = sel[b * 4 + 0];
    size_t base = (size_t)b * NN + (size_t)blockIdx.x * CHUNK_H;
    #pragma unroll 4
    for (int it = 0; it < HITER; ++it) {
        float2 p = probs2[base + it * 256 + threadIdx.x];
        u32 key = __float_as_uint(p.y);
        if ((key >> 21) == b1) atomicAdd(&hist2[b * 2048 + ((key >> 10) & 2047u)], 1u);
    }
}

__global__ void k_sel2(const u32* __restrict__ hist2, u32* __restrict__ sel) {
    __shared__ u32 gsum[256];
    __shared__ u32 lh[2048];
    int b = blockIdx.x;
    int t = threadIdx.x;
    u32 s = 0;
    #pragma unroll
    for (int j = 0; j < 8; ++j) {
        u32 v = hist2[b * 2048 + 2047 - (t * 8 + j)];
        lh[t * 8 + j] = v;
        s += v;
    }
    gsum[t] = s;
    __syncthreads();
    if (t == 0) {
        u32 cum = sel[b * 4 + 1];
        u32 b1 = sel[b * 4 + 0];
        for (int g = 0; g < 256; ++g) {
            if (cum + gsum[g] >= (u32)KSEL) {
                for (int j = 0; j < 8; ++j) {
                    cum += lh[g * 8 + j];
                    if (cum >= (u32)KSEL) {
                        sel[b * 4 + 2] = (b1 << 11) | (u32)(2047 - (g * 8 + j));
                        break;
                    }
                }
                break;
            }
            cum += gsum[g];
        }
    }
}

// block-aggregated compaction: one global atomic per block, ballot-scan placement.
__global__ void k_compact(const float2* __restrict__ probs2, const u32* __restrict__ sel,
                          u32* __restrict__ candCount, u64* __restrict__ cand) {
    __shared__ u32 wsum[4];
    __shared__ u32 blkBase;
    int b = blockIdx.y;
    int tid = threadIdx.x;
    int wave = tid >> 6, lane = tid & 63;
    u32 base = (u32)blockIdx.x * CHUNK_C;
    u32 thr = sel[b * 4 + 2];

    u32 keys[CITER];
    u32 cnt = 0;
    #pragma unroll
    for (int it = 0; it < CITER; ++it) {
        float2 p = probs2[(size_t)b * NN + base + it * 256 + tid];
        u32 key = __float_as_uint(p.y);
        keys[it] = key;
        cnt += ((key >> 10) >= thr) ? 1u : 0u;
    }
    #pragma unroll
    for (int off = 32; off; off >>= 1) cnt += __shfl_down(cnt, off);
    if (lane == 0) wsum[wave] = cnt;
    __syncthreads();
    if (tid == 0) {
        u32 w0 = wsum[0], w1 = wsum[1], w2 = wsum[2], w3 = wsum[3];
        u32 tot = w0 + w1 + w2 + w3;
        wsum[0] = 0; wsum[1] = w0; wsum[2] = w0 + w1; wsum[3] = w0 + w1 + w2;
        blkBase = tot ? atomicAdd(&candCount[b * 32], tot) : 0u;
    }
    __syncthreads();
    u32 run = blkBase + wsum[wave];
    u64* cb = cand + (size_t)b * CAP;
    #pragma unroll
    for (int it = 0; it < CITER; ++it) {
        u32 key = keys[it];
        bool pred = (key >> 10) >= thr;
        u64 m = __ballot(pred);
        if (pred) {
            u32 pos = run + (u32)__popcll(m & ((1ull << lane) - 1ull));
            u32 gi = base + it * 256 + tid;
            if (pos < CAP) cb[pos] = ((u64)key << 32) | (u32)(~gi);
        }
        run += (u32)__popcll(m);
    }
}

// ---------- rank-by-counting sort: rank(i) = #{j : key[j] > key[i]} ----------
__global__ __launch_bounds__(512) void k_rank(const u64* __restrict__ cand,
                                              const u32* __restrict__ candCount,
                                              u64* __restrict__ sorted) {
    __shared__ u64 keys[CAP];   // 64 KB
    int b = blockIdx.y;
    int tid = threadIdx.x;
    int cnt = (int)candCount[b * 32];
    if (cnt > CAP) cnt = CAP;
    const u64* cb = cand + (size_t)b * CAP;
    for (int j = tid; j < CAP; j += 512)
        keys[j] = (j < cnt) ? cb[j] : 0ull;   // 0 never outranks a real key
    __syncthreads();
    int r = blockIdx.x * 512 + tid;
    if (r >= cnt) return;
    u64 my = keys[r];
    int cnt16 = (cnt + 15) & ~15;
    int rank = 0;
    for (int j = 0; j < cnt16; j += 16) {
        #pragma unroll
        for (int u = 0; u < 16; ++u)
            rank += (keys[j + u] > my) ? 1 : 0;
    }
    if (rank < KSEL) sorted[(size_t)b * KSEL + rank] = my;
}

// ---------- decode top-KSEL sorted records into clipped boxes ----------
__global__ void k_decode(const u64* __restrict__ sorted,
                         const float4* __restrict__ anchors, const float4* __restrict__ deltas,
                         float4* __restrict__ boxes) {
    int b = blockIdx.y;
    int t = blockIdx.x * 256 + threadIdx.x;
    if (t >= KSEL) return;
    u64 sk = sorted[(size_t)b * KSEL + t];
    u32 idx = ~(u32)(sk & 0xFFFFFFFFull);
    if (idx >= NN) idx = NN - 1;   // poison-safety; unreachable in normal path
    float4 a = anchors[(size_t)b * NN + idx];
    float4 d = deltas[(size_t)b * NN + idx];
    float dy = __fmul_rn(d.x, 0.1f);
    float dx = __fmul_rn(d.y, 0.1f);
    float dh = __fmul_rn(d.z, 0.2f);
    float dw = __fmul_rn(d.w, 0.2f);
    float h  = __fsub_rn(a.z, a.x);
    float w  = __fsub_rn(a.w, a.y);
    float cy = __fadd_rn(__fadd_rn(a.x, __fmul_rn(0.5f, h)), __fmul_rn(dy, h));
    float cx = __fadd_rn(__fadd_rn(a.y, __fmul_rn(0.5f, w)), __fmul_rn(dx, w));
    float h2 = __fmul_rn(h, expf(dh));
    float w2 = __fmul_rn(w, expf(dw));
    float y1 = __fsub_rn(cy, __fmul_rn(0.5f, h2));
    float x1 = __fsub_rn(cx, __fmul_rn(0.5f, w2));
    float y2 = __fadd_rn(y1, h2);
    float x2 = __fadd_rn(x1, w2);
    y1 = fminf(fmaxf(y1, 0.0f), 1.0f);
    x1 = fminf(fmaxf(x1, 0.0f), 1.0f);
    y2 = fminf(fmaxf(y2, 0.0f), 1.0f);
    x2 = fminf(fmaxf(x2, 0.0f), 1.0f);
    float4 out;
    out.x = y1; out.y = x1; out.z = y2; out.w = x2;
    boxes[(size_t)b * KSEL + t] = out;
}

// ---------- fallback: single-block bitonic sort+gather (ws too small) ----------
__global__ void k_sortgather(const u64* __restrict__ cand, const u32* __restrict__ candCount,
                             const float4* __restrict__ anchors, const float4* __restrict__ deltas,
                             float4* __restrict__ boxes) {
    __shared__ u64 s[CAP];   // exactly 64 KB
    int b = blockIdx.x;
    int tid = threadIdx.x;
    u32 cnt = candCount[b * 32];
    if (cnt > CAP) cnt = CAP;
    for (int j = tid; j < CAP; j += 1024)
        s[j] = (j < (int)cnt) ? cand[(size_t)b * CAP + j] : 0ull;
    __syncthreads();
    for (int k = 2; k <= CAP; k <<= 1) {
        for (int j = k >> 1; j > 0; j >>= 1) {
            for (int idx = tid; idx < CAP; idx += 1024) {
                int l = idx ^ j;
                if (l > idx) {
                    u64 a = s[idx], c = s[l];
                    bool dir = ((idx & k) == 0);
                    if ((a < c) == dir) { s[idx] = c; s[l] = a; }
                }
            }
            __syncthreads();
        }
    }
    for (int t = tid; t < KSEL; t += 1024) {
        u64 sk = s[t];
        u32 idx = ~(u32)(sk & 0xFFFFFFFFull);
        float4 a = anchors[(size_t)b * NN + idx];
        float4 d = deltas[(size_t)b * NN + idx];
        float dy = __fmul_rn(d.x, 0.1f);
        float dx = __fmul_rn(d.y, 0.1f);
        float dh = __fmul_rn(d.z, 0.2f);
        float dw = __fmul_rn(d.w, 0.2f);
        float h  = __fsub_rn(a.z, a.x);
        float w  = __fsub_rn(a.w, a.y);
        float cy = __fadd_rn(__fadd_rn(a.x, __fmul_rn(0.5f, h)), __fmul_rn(dy, h));
        float cx = __fadd_rn(__fadd_rn(a.y, __fmul_rn(0.5f, w)), __fmul_rn(dx, w));
        float h2 = __fmul_rn(h, expf(dh));
        float w2 = __fmul_rn(w, expf(dw));
        float y1 = __fsub_rn(cy, __fmul_rn(0.5f, h2));
        float x1 = __fsub_rn(cx, __fmul_rn(0.5f, w2));
        float y2 = __fadd_rn(y1, h2);
        float x2 = __fadd_rn(x1, w2);
        y1 = fminf(fmaxf(y1, 0.0f), 1.0f);
        x1 = fminf(fmaxf(x1, 0.0f), 1.0f);
        y2 = fminf(fmaxf(y2, 0.0f), 1.0f);
        x2 = fminf(fmaxf(x2, 0.0f), 1.0f);
        float4 out;
        out.x = y1; out.y = x1; out.z = y2; out.w = x2;
        boxes[(size_t)b * KSEL + t] = out;
    }
}

// ---------- phase 1: UPPER-TRIANGLE suppression bitmask, lane = row ----------
// COLUMN-MAJOR mask: Mb[jw*NR + row]. Wave's 64 lanes store 64 consecutive
// u64 (512B contiguous) — coalesced. Only jw >= rblk written (upper triangle);
// unwritten words are never consulted by k_reduce (proof in R8: DECIDE(g)
// reads lane g of the OR; rows accumulated before DECIDE(g) have group < g,
// their garbage words sit at lanes < g).
// Exact division-free test: fl(inter/denom) > 0.7f <=> inter >= M0*denom in
// double, M0 = midpoint(0.7f, nextafterf(0.7f)); exact since M0 has 25
// mantissa bits and denom 24.
__global__ __launch_bounds__(256) void k_iou(const float4* __restrict__ boxes,
                                             u64* __restrict__ mask) {
    __shared__ float4 colBox[4][64];
    __shared__ float  colArea[4][64];
    int b = blockIdx.z;
    int rblk = blockIdx.x;
    int r0 = rblk * 64;
    int tid = threadIdx.x;
    int wave = tid >> 6, lane = tid & 63;
    const float4* B4 = boxes + (size_t)b * KSEL;

    int r = r0 + lane;
    float4 rb;
    if (r < KSEL) rb = B4[r];
    else { rb.x = 2.0f; rb.y = 2.0f; rb.z = 3.0f; rb.w = 3.0f; }
    float ra = __fmul_rn(__fsub_rn(rb.z, rb.x), __fsub_rn(rb.w, rb.y));

    const double M0 = 0.5 * ((double)__uint_as_float(0x3F333333u)
                           + (double)__uint_as_float(0x3F333334u));
    u64* Mb = mask + (size_t)b * NW * NR;

    for (int jw = rblk + blockIdx.y * 4 + wave; jw < NW; jw += 4 * COLSPLIT) {
        int j = jw * 64 + lane;
        float4 cbx;
        if (j < KSEL) cbx = B4[j];
        else { cbx.x = 2.0f; cbx.y = 2.0f; cbx.z = 3.0f; cbx.w = 3.0f; }
        colBox[wave][lane] = cbx;
        colArea[wave][lane] = __fmul_rn(__fsub_rn(cbx.z, cbx.x), __fsub_rn(cbx.w, cbx.y));
        asm volatile("" ::: "memory");   // pin LDS write->read ordering (same wave)

        u64 word = 0ull;
        #pragma unroll
        for (int c = 0; c < 64; ++c) {
            float4 cb = colBox[wave][c];
            float ca = colArea[wave][c];
            float ih = fmaxf(__fsub_rn(fminf(rb.z, cb.z), fmaxf(rb.x, cb.x)), 0.0f);
            float iw = fmaxf(__fsub_rn(fminf(rb.w, cb.w), fmaxf(rb.y, cb.y)), 0.0f);
            float inter = __fmul_rn(ih, iw);
            float denom = __fadd_rn(__fsub_rn(__fadd_rn(ra, ca), inter), 1e-8f);
            bool pred = ((double)inter >= M0 * (double)denom);
            word |= ((u64)pred) << c;
        }
        Mb[(size_t)jw * NR + (r0 + lane)] = word;   // coalesced 512B per wave
        asm volatile("" ::: "memory");   // keep LDS rewrite of next iter behind reads
    }
}

// ---------- phase 2: scalar-chain reduce, one wave per batch ----------
// Column-major mask: lane l streams word l (and word hiw) as CONTIGUOUS u64
// runs over rows -> dwordx4 loads, 8 wide loads per 8-row chunk (vs 16 narrow)
// so the 63-outstanding-load cap covers an 8-chunk (full-group) register ring.
__device__ __forceinline__ u64 readlane64(u64 v, int lane) {
    u32 lo = (u32)__builtin_amdgcn_readlane((int)(u32)v, lane);
    u32 hi = (u32)__builtin_amdgcn_readlane((int)(u32)(v >> 32), lane);
    return ((u64)hi << 32) | (u64)lo;
}

#define LOADC8(LO, HI, chunk) do {                                            \
    int ck_ = (chunk); if (ck_ > (NR/8 - 1)) ck_ = NR/8 - 1;                  \
    const ulonglong2* plo_ = (const ulonglong2*)(Mlo + (size_t)ck_ * 8);      \
    const ulonglong2* phi_ = (const ulonglong2*)(Mhi + (size_t)ck_ * 8);      \
    _Pragma("unroll")                                                         \
    for (int q_ = 0; q_ < 4; ++q_) {                                          \
        ulonglong2 a_ = plo_[q_]; LO[2*q_] = a_.x; LO[2*q_+1] = a_.y;         \
        ulonglong2 b_ = phi_[q_]; HI[2*q_] = b_.x; HI[2*q_+1] = b_.y;         \
    }                                                                         \
} while (0)

#define ACCUM(LO, HI, base) do {                                              \
    _Pragma("unroll")                                                         \
    for (int r_ = 0; r_ < 8; ++r_) {                                          \
        if ((kb >> ((base) + r_)) & 1ull) { rwLo |= LO[r_]; rwHi |= HI[r_]; } \
    }                                                                         \
} while (0)

#define DIAG(DST, g) do {                                                     \
    int gg_ = (g) < NW ? (g) : NW - 1;                                        \
    DST = M[(size_t)gg_ * NR + (size_t)gg_ * 64 + lane];                      \
} while (0)

#define DECIDE(g, DG) do {                                                    \
    u64 rem_ = ((g) < 64) ? readlane64(rwLo, (g)) : readlane64(rwHi, (g) - 64); \
    int remaining_ = KSEL - (g) * 64;                                         \
    u64 valid_ = (remaining_ >= 64) ? ~0ull : ((1ull << remaining_) - 1ull);  \
    u64 todo_ = ~rem_ & valid_;                                               \
    kb = 0ull;                                                                \
    while (todo_ && k < PC) {                                                 \
        int i_ = (int)__builtin_ctzll(todo_);                                 \
        kb |= (1ull << i_);                                                   \
        ++k;                                                                  \
        u64 drow_ = readlane64(DG, i_);                                       \
        todo_ &= ~(drow_ | (1ull << i_));                                     \
    }                                                                         \
    if ((kb >> lane) & 1ull) {                                                \
        int rank_ = kprev + (int)__popcll(kb & ((1ull << lane) - 1ull));      \
        keptIdx[rank_] = (u32)((g) * 64 + lane);                              \
    }                                                                         \
    kprev = k;                                                                \
} while (0)

__global__ __launch_bounds__(64) void k_reduce(const u64* __restrict__ mask,
                                               const float4* __restrict__ boxes,
                                               float* __restrict__ outp) {
    __shared__ u32 keptIdx[PC];
    int b = blockIdx.x;
    int lane = threadIdx.x;
    const u64* M = mask + (size_t)b * NW * NR;
    const float4* B4 = boxes + (size_t)b * KSEL;
    int hiw = (lane < (NW - 64)) ? (64 + lane) : (NW - 1);
    const u64* Mlo = M + (size_t)lane * NR;
    const u64* Mhi = M + (size_t)hiw * NR;
    u64 rwLo = 0ull, rwHi = 0ull;

    u64 bLo[8][8], bHi[8][8];
    u64 dgA, dgB;
    int k = 0, kprev = 0;
    u64 kb;

    #pragma unroll
    for (int c = 0; c < 8; ++c) LOADC8(bLo[c], bHi[c], c);
    DIAG(dgA, 0);
    DIAG(dgB, 1);

    for (int g = 0; g < NW; ++g) {
        if (g & 1) { DECIDE(g, dgB); DIAG(dgB, g + 2); }
        else       { DECIDE(g, dgA); DIAG(dgA, g + 2); }
        if (k >= PC) break;
        #pragma unroll
        for (int c = 0; c < 8; ++c) {
            ACCUM(bLo[c], bHi[c], c * 8);
            LOADC8(bLo[c], bHi[c], (g + 1) * 8 + c);
        }
    }
    __syncthreads();

    float4* O = (float4*)outp + (size_t)b * PC;
    for (int t = lane; t < PC; t += 64) {
        float4 v; v.x = 0.0f; v.y = 0.0f; v.z = 0.0f; v.w = 0.0f;
        if (t < k) v = B4[keptIdx[t]];
        O[t] = v;
    }
}

// ---------- fallback serial NMS (used only if ws too small for mask) ----------
__global__ void k_nms(const float4* __restrict__ boxes, float* __restrict__ outp) {
    __shared__ float4 chunk[512];
    __shared__ float4 keptBox[PC];
    __shared__ float  keptArea[PC];
    __shared__ u32    flag[2];
    int b = blockIdx.x;
    int tid = threadIdx.x;
    const float4* B4 = boxes + (size_t)b * KSEL;

    if (tid < 2) flag[tid] = 0u;
    for (int j = tid; j < 512; j += 256) chunk[j] = B4[j];
    __syncthreads();

    int kc = 0;
    for (int i = 0; i < KSEL && kc < PC; ++i) {
        int ci = i & 511;
        if (ci == 0 && i != 0) {
            for (int j = tid; j < 512 && (i + j) < KSEL; j += 256) chunk[j] = B4[i + j];
            __syncthreads();
        }
        float4 cb = chunk[ci];
        float careaV = __fmul_rn(__fsub_rn(cb.z, cb.x), __fsub_rn(cb.w, cb.y));
        bool sup = false;
        for (int t = tid; t < kc; t += 256) {
            float4 kb2 = keptBox[t];
            float ih = fmaxf(__fsub_rn(fminf(cb.z, kb2.z), fmaxf(cb.x, kb2.x)), 0.0f);
            float iw = fmaxf(__fsub_rn(fminf(cb.w, kb2.w), fmaxf(cb.y, kb2.y)), 0.0f);
            float inter = __fmul_rn(ih, iw);
            float denom = __fadd_rn(__fsub_rn(__fadd_rn(careaV, keptArea[t]), inter), 1e-8f);
            if (__fdiv_rn(inter, denom) > NMS_THR) sup = true;
        }
        int p = i & 1;
        if (sup) flag[p] = 1u;
        if (tid == 0) flag[p ^ 1] = 0u;
        __syncthreads();
        if (flag[p] == 0u) {
            if (tid == 0) { keptBox[kc] = cb; keptArea[kc] = careaV; }
            kc++;
        }
        __syncthreads();
    }

    float4* out4 = (float4*)outp + (size_t)b * PC;
    for (int r = tid; r < PC; r += 256) {
        float4 v;
        if (r < kc) v = keptBox[r];
        else { v.x = 0.0f; v.y = 0.0f; v.z = 0.0f; v.w = 0.0f; }
        out4[r] = v;
    }
}

extern "C" void kernel_launch(void* const* d_in, const int* in_sizes, int n_in,
                              void* d_out, int out_size, void* d_ws, size_t ws_size,
                              hipStream_t stream) {
    const float* probs   = (const float*)d_in[0];
    const float* deltas  = (const float*)d_in[1];
    const float* anchors = (const float*)d_in[2];
    float* outp = (float*)d_out;

    u32* ws32 = (u32*)d_ws;
    u32* hist1 = ws32 + HIST1_OFF;
    u32* hist2 = ws32 + HIST2_OFF;
    u32* sel   = ws32 + SEL_OFF;
    u32* candCount = ws32 + CNT_OFF;
    u64* cand   = (u64*)(ws32 + ZERO_WORDS);
    u64* sorted = cand + (size_t)BB * CAP;
    float* boxesF = (float*)(sorted + (size_t)BB * KSEL);
    float4* boxes = (float4*)boxesF;
    u64* mask = (u64*)(boxesF + (size_t)BB * KSEL * 4);

    size_t needed = (size_t)ZERO_WORDS * 4 + (size_t)BB * CAP * 8 + (size_t)BB * KSEL * 8
                  + (size_t)BB * KSEL * 16 + (size_t)BB * NW * NR * 8;

    hipLaunchKernelGGL(k_zero, dim3((ZERO_WORDS + 255) / 256), dim3(256), 0, stream, ws32);
    hipLaunchKernelGGL(k_hist1, dim3(HB, BB), dim3(256), 0, stream, (const float2*)probs, hist1);
    hipLaunchKernelGGL(k_sel1, dim3(BB), dim3(256), 0, stream, hist1, sel);
    hipLaunchKernelGGL(k_hist2, dim3(HB, BB), dim3(256), 0, stream, (const float2*)probs, sel, hist2);
    hipLaunchKernelGGL(k_sel2, dim3(BB), dim3(256), 0, stream, hist2, sel);
    hipLaunchKernelGGL(k_compact, dim3(CB, BB), dim3(256), 0, stream, (const float2*)probs, sel, candCount, cand);
    if (ws_size >= needed) {
        hipLaunchKernelGGL(k_rank, dim3(CAP / 512, BB), dim3(512), 0, stream, cand, candCount, sorted);
        hipLaunchKernelGGL(k_decode, dim3((KSEL + 255) / 256, BB), dim3(256), 0, stream,
                           sorted, (const float4*)anchors, (const float4*)deltas, boxes);
        hipLaunchKernelGGL(k_iou, dim3(NW, COLSPLIT, BB), dim3(256), 0, stream, boxes, mask);
        hipLaunchKernelGGL(k_reduce, dim3(BB), dim3(64), 0, stream, mask, boxes, outp);
    } else {
        hipLaunchKernelGGL(k_sortgather, dim3(BB), dim3(1024), 0, stream,
                           cand, candCount, (const float4*)anchors, (const float4*)deltas, boxes);
        hipLaunchKernelGGL(k_nms, dim3(BB), dim3(256), 0, stream, boxes, outp);
    }
}

// Round 11
// 277.264 us; speedup vs baseline: 1.1564x; 1.1564x over previous
//
#include <hip/hip_runtime.h>

typedef unsigned int u32;
typedef unsigned long long u64;

#define BB 4
#define NN 261888
#define KSEL 6000
#define CAP 8192
#define PC 1000
#define NMS_THR 0.7f
#define NW 94          /* ceil(KSEL/64) */
#define NR (NW*64)     /* padded mask rows = 6016 */
#define COLSPLIT 6     /* k_iou column-range split for occupancy */

#define HB 31                    /* hist blocks per batch */
#define CHUNK_H (NN/HB)          /* 8448 = 33*256 */
#define HITER (CHUNK_H/256)      /* 33 */
#define CB 93                    /* compact blocks per batch */
#define CHUNK_C (NN/CB)          /* 2816 = 11*256 */
#define CITER (CHUNK_C/256)      /* 11 */

// ---------------- ws layout (u32 units) ----------------
// hist1: BB*2048 | hist2: BB*2048 | sel: BB*4 | candCount: BB*32 (128B-padded) |
// cand(u64): BB*CAP | sorted(u64): BB*KSEL | boxes(f32): BB*KSEL*4 |
// mask(u64): BB*NR*NW  (ROW-MAJOR: mask[b][row][word], row stride 752B = 16B-aligned)
#define HIST1_OFF 0
#define HIST2_OFF (BB*2048)
#define SEL_OFF   (BB*2048*2)
#define CNT_OFF   (BB*2048*2 + BB*4)
#define ZERO_WORDS (BB*2048*2 + BB*4 + BB*32)

__global__ void k_zero(u32* ws) {
    int i = blockIdx.x * 256 + threadIdx.x;
    if (i < ZERO_WORDS) ws[i] = 0u;
}

__global__ void k_hist1(const float2* __restrict__ probs2, u32* __restrict__ hist1) {
    __shared__ u32 lh[2048];
    int b = blockIdx.y;
    size_t base = (size_t)b * NN + (size_t)blockIdx.x * CHUNK_H;
    for (int j = threadIdx.x; j < 2048; j += 256) lh[j] = 0u;
    __syncthreads();
    #pragma unroll 4
    for (int it = 0; it < HITER; ++it) {
        float2 p = probs2[base + it * 256 + threadIdx.x];
        atomicAdd(&lh[__float_as_uint(p.y) >> 21], 1u);
    }
    __syncthreads();
    for (int j = threadIdx.x; j < 2048; j += 256) {
        u32 c = lh[j];
        if (c) atomicAdd(&hist1[b * 2048 + j], c);
    }
}

// descending-group scan: thread t owns bins 2047-8t .. 2047-8t-7
__global__ void k_sel1(const u32* __restrict__ hist1, u32* __restrict__ sel) {
    __shared__ u32 gsum[256];
    __shared__ u32 lh[2048];    // lh[k] = hist[2047-k]
    int b = blockIdx.x;
    int t = threadIdx.x;
    u32 s = 0;
    #pragma unroll
    for (int j = 0; j < 8; ++j) {
        u32 v = hist1[b * 2048 + 2047 - (t * 8 + j)];
        lh[t * 8 + j] = v;
        s += v;
    }
    gsum[t] = s;
    __syncthreads();
    if (t == 0) {
        u32 cum = 0;
        for (int g = 0; g < 256; ++g) {
            if (cum + gsum[g] >= (u32)KSEL) {
                for (int j = 0; j < 8; ++j) {
                    u32 c = lh[g * 8 + j];
                    if (cum + c >= (u32)KSEL) {
                        sel[b * 4 + 0] = (u32)(2047 - (g * 8 + j));
                        sel[b * 4 + 1] = cum;
                        break;
                    }
                    cum += c;
                }
                break;
            }
            cum += gsum[g];
        }
    }
}

__global__ void k_hist2(const float2* __restrict__ probs2, const u32* __restrict__ sel,
                        u32* __restrict__ hist2) {
    int b = blockIdx.y;
    u32 b1 = sel[b * 4 + 0];
    size_t base = (size_t)b * NN + (size_t)blockIdx.x * CHUNK_H;
    #pragma unroll 4
    for (int it = 0; it < HITER; ++it) {
        float2 p = probs2[base + it * 256 + threadIdx.x];
        u32 key = __float_as_uint(p.y);
        if ((key >> 21) == b1) atomicAdd(&hist2[b * 2048 + ((key >> 10) & 2047u)], 1u);
    }
}

__global__ void k_sel2(const u32* __restrict__ hist2, u32* __restrict__ sel) {
    __shared__ u32 gsum[256];
    __shared__ u32 lh[2048];
    int b = blockIdx.x;
    int t = threadIdx.x;
    u32 s = 0;
    #pragma unroll
    for (int j = 0; j < 8; ++j) {
        u32 v = hist2[b * 2048 + 2047 - (t * 8 + j)];
        lh[t * 8 + j] = v;
        s += v;
    }
    gsum[t] = s;
    __syncthreads();
    if (t == 0) {
        u32 cum = sel[b * 4 + 1];
        u32 b1 = sel[b * 4 + 0];
        for (int g = 0; g < 256; ++g) {
            if (cum + gsum[g] >= (u32)KSEL) {
                for (int j = 0; j < 8; ++j) {
                    cum += lh[g * 8 + j];
                    if (cum >= (u32)KSEL) {
                        sel[b * 4 + 2] = (b1 << 11) | (u32)(2047 - (g * 8 + j));
                        break;
                    }
                }
                break;
            }
            cum += gsum[g];
        }
    }
}

// block-aggregated compaction: one global atomic per block, ballot-scan placement.
__global__ void k_compact(const float2* __restrict__ probs2, const u32* __restrict__ sel,
                          u32* __restrict__ candCount, u64* __restrict__ cand) {
    __shared__ u32 wsum[4];
    __shared__ u32 blkBase;
    int b = blockIdx.y;
    int tid = threadIdx.x;
    int wave = tid >> 6, lane = tid & 63;
    u32 base = (u32)blockIdx.x * CHUNK_C;
    u32 thr = sel[b * 4 + 2];

    u32 keys[CITER];
    u32 cnt = 0;
    #pragma unroll
    for (int it = 0; it < CITER; ++it) {
        float2 p = probs2[(size_t)b * NN + base + it * 256 + tid];
        u32 key = __float_as_uint(p.y);
        keys[it] = key;
        cnt += ((key >> 10) >= thr) ? 1u : 0u;
    }
    #pragma unroll
    for (int off = 32; off; off >>= 1) cnt += __shfl_down(cnt, off);
    if (lane == 0) wsum[wave] = cnt;
    __syncthreads();
    if (tid == 0) {
        u32 w0 = wsum[0], w1 = wsum[1], w2 = wsum[2], w3 = wsum[3];
        u32 tot = w0 + w1 + w2 + w3;
        wsum[0] = 0; wsum[1] = w0; wsum[2] = w0 + w1; wsum[3] = w0 + w1 + w2;
        blkBase = tot ? atomicAdd(&candCount[b * 32], tot) : 0u;
    }
    __syncthreads();
    u32 run = blkBase + wsum[wave];
    u64* cb = cand + (size_t)b * CAP;
    #pragma unroll
    for (int it = 0; it < CITER; ++it) {
        u32 key = keys[it];
        bool pred = (key >> 10) >= thr;
        u64 m = __ballot(pred);
        if (pred) {
            u32 pos = run + (u32)__popcll(m & ((1ull << lane) - 1ull));
            u32 gi = base + it * 256 + tid;
            if (pos < CAP) cb[pos] = ((u64)key << 32) | (u32)(~gi);
        }
        run += (u32)__popcll(m);
    }
}

// ---------- rank-by-counting sort: rank(i) = #{j : key[j] > key[i]} ----------
__global__ __launch_bounds__(512) void k_rank(const u64* __restrict__ cand,
                                              const u32* __restrict__ candCount,
                                              u64* __restrict__ sorted) {
    __shared__ u64 keys[CAP];   // 64 KB
    int b = blockIdx.y;
    int tid = threadIdx.x;
    int cnt = (int)candCount[b * 32];
    if (cnt > CAP) cnt = CAP;
    const u64* cb = cand + (size_t)b * CAP;
    for (int j = tid; j < CAP; j += 512)
        keys[j] = (j < cnt) ? cb[j] : 0ull;   // 0 never outranks a real key
    __syncthreads();
    int r = blockIdx.x * 512 + tid;
    if (r >= cnt) return;
    u64 my = keys[r];
    int cnt16 = (cnt + 15) & ~15;
    int rank = 0;
    for (int j = 0; j < cnt16; j += 16) {
        #pragma unroll
        for (int u = 0; u < 16; ++u)
            rank += (keys[j + u] > my) ? 1 : 0;
    }
    if (rank < KSEL) sorted[(size_t)b * KSEL + rank] = my;
}

// ---------- decode top-KSEL sorted records into clipped boxes ----------
__global__ void k_decode(const u64* __restrict__ sorted,
                         const float4* __restrict__ anchors, const float4* __restrict__ deltas,
                         float4* __restrict__ boxes) {
    int b = blockIdx.y;
    int t = blockIdx.x * 256 + threadIdx.x;
    if (t >= KSEL) return;
    u64 sk = sorted[(size_t)b * KSEL + t];
    u32 idx = ~(u32)(sk & 0xFFFFFFFFull);
    if (idx >= NN) idx = NN - 1;   // poison-safety; unreachable in normal path
    float4 a = anchors[(size_t)b * NN + idx];
    float4 d = deltas[(size_t)b * NN + idx];
    float dy = __fmul_rn(d.x, 0.1f);
    float dx = __fmul_rn(d.y, 0.1f);
    float dh = __fmul_rn(d.z, 0.2f);
    float dw = __fmul_rn(d.w, 0.2f);
    float h  = __fsub_rn(a.z, a.x);
    float w  = __fsub_rn(a.w, a.y);
    float cy = __fadd_rn(__fadd_rn(a.x, __fmul_rn(0.5f, h)), __fmul_rn(dy, h));
    float cx = __fadd_rn(__fadd_rn(a.y, __fmul_rn(0.5f, w)), __fmul_rn(dx, w));
    float h2 = __fmul_rn(h, expf(dh));
    float w2 = __fmul_rn(w, expf(dw));
    float y1 = __fsub_rn(cy, __fmul_rn(0.5f, h2));
    float x1 = __fsub_rn(cx, __fmul_rn(0.5f, w2));
    float y2 = __fadd_rn(y1, h2);
    float x2 = __fadd_rn(x1, w2);
    y1 = fminf(fmaxf(y1, 0.0f), 1.0f);
    x1 = fminf(fmaxf(x1, 0.0f), 1.0f);
    y2 = fminf(fmaxf(y2, 0.0f), 1.0f);
    x2 = fminf(fmaxf(x2, 0.0f), 1.0f);
    float4 out;
    out.x = y1; out.y = x1; out.z = y2; out.w = x2;
    boxes[(size_t)b * KSEL + t] = out;
}

// ---------- fallback: single-block bitonic sort+gather (ws too small) ----------
__global__ void k_sortgather(const u64* __restrict__ cand, const u32* __restrict__ candCount,
                             const float4* __restrict__ anchors, const float4* __restrict__ deltas,
                             float4* __restrict__ boxes) {
    __shared__ u64 s[CAP];   // exactly 64 KB
    int b = blockIdx.x;
    int tid = threadIdx.x;
    u32 cnt = candCount[b * 32];
    if (cnt > CAP) cnt = CAP;
    for (int j = tid; j < CAP; j += 1024)
        s[j] = (j < (int)cnt) ? cand[(size_t)b * CAP + j] : 0ull;
    __syncthreads();
    for (int k = 2; k <= CAP; k <<= 1) {
        for (int j = k >> 1; j > 0; j >>= 1) {
            for (int idx = tid; idx < CAP; idx += 1024) {
                int l = idx ^ j;
                if (l > idx) {
                    u64 a = s[idx], c = s[l];
                    bool dir = ((idx & k) == 0);
                    if ((a < c) == dir) { s[idx] = c; s[l] = a; }
                }
            }
            __syncthreads();
        }
    }
    for (int t = tid; t < KSEL; t += 1024) {
        u64 sk = s[t];
        u32 idx = ~(u32)(sk & 0xFFFFFFFFull);
        float4 a = anchors[(size_t)b * NN + idx];
        float4 d = deltas[(size_t)b * NN + idx];
        float dy = __fmul_rn(d.x, 0.1f);
        float dx = __fmul_rn(d.y, 0.1f);
        float dh = __fmul_rn(d.z, 0.2f);
        float dw = __fmul_rn(d.w, 0.2f);
        float h  = __fsub_rn(a.z, a.x);
        float w  = __fsub_rn(a.w, a.y);
        float cy = __fadd_rn(__fadd_rn(a.x, __fmul_rn(0.5f, h)), __fmul_rn(dy, h));
        float cx = __fadd_rn(__fadd_rn(a.y, __fmul_rn(0.5f, w)), __fmul_rn(dx, w));
        float h2 = __fmul_rn(h, expf(dh));
        float w2 = __fmul_rn(w, expf(dw));
        float y1 = __fsub_rn(cy, __fmul_rn(0.5f, h2));
        float x1 = __fsub_rn(cx, __fmul_rn(0.5f, w2));
        float y2 = __fadd_rn(y1, h2);
        float x2 = __fadd_rn(x1, w2);
        y1 = fminf(fmaxf(y1, 0.0f), 1.0f);
        x1 = fminf(fmaxf(x1, 0.0f), 1.0f);
        y2 = fminf(fmaxf(y2, 0.0f), 1.0f);
        x2 = fminf(fmaxf(x2, 0.0f), 1.0f);
        float4 out;
        out.x = y1; out.y = x1; out.z = y2; out.w = x2;
        boxes[(size_t)b * KSEL + t] = out;
    }
}

// ---------- phase 1: UPPER-TRIANGLE suppression bitmask, lane = row ----------
// ROW-MAJOR mask: Mb[row*NW + jw]. Only jw >= rblk written (upper triangle);
// unwritten words never consulted by k_reduce: DECIDE(g) reads word g of the
// OR over rows of groups < g; word g of a group-h row with h <= g-1 has
// g >= h -> written. Garbage words jw < h only pollute rw words whose DECIDE
// already happened. Pad rows/cols use far box (2,2,3,3), masked by valid_.
// Exact division-free test: fl(inter/denom) > 0.7f <=> inter >= M0*denom in
// double, M0 = midpoint(0.7f, nextafterf(0.7f)); exact (M0 25 bits x 24 bits).
__global__ __launch_bounds__(256) void k_iou(const float4* __restrict__ boxes,
                                             u64* __restrict__ mask) {
    __shared__ float4 colBox[4][64];
    __shared__ float  colArea[4][64];
    int b = blockIdx.z;
    int rblk = blockIdx.x;
    int r0 = rblk * 64;
    int tid = threadIdx.x;
    int wave = tid >> 6, lane = tid & 63;
    const float4* B4 = boxes + (size_t)b * KSEL;

    int r = r0 + lane;
    float4 rb;
    if (r < KSEL) rb = B4[r];
    else { rb.x = 2.0f; rb.y = 2.0f; rb.z = 3.0f; rb.w = 3.0f; }
    float ra = __fmul_rn(__fsub_rn(rb.z, rb.x), __fsub_rn(rb.w, rb.y));

    const double M0 = 0.5 * ((double)__uint_as_float(0x3F333333u)
                           + (double)__uint_as_float(0x3F333334u));
    u64* Mb = mask + (size_t)b * NR * NW;

    for (int jw = rblk + blockIdx.y * 4 + wave; jw < NW; jw += 4 * COLSPLIT) {
        int j = jw * 64 + lane;
        float4 cbx;
        if (j < KSEL) cbx = B4[j];
        else { cbx.x = 2.0f; cbx.y = 2.0f; cbx.z = 3.0f; cbx.w = 3.0f; }
        colBox[wave][lane] = cbx;
        colArea[wave][lane] = __fmul_rn(__fsub_rn(cbx.z, cbx.x), __fsub_rn(cbx.w, cbx.y));
        asm volatile("" ::: "memory");   // pin LDS write->read ordering (same wave)

        u64 word = 0ull;
        #pragma unroll
        for (int c = 0; c < 64; ++c) {
            float4 cb = colBox[wave][c];
            float ca = colArea[wave][c];
            float ih = fmaxf(__fsub_rn(fminf(rb.z, cb.z), fmaxf(rb.x, cb.x)), 0.0f);
            float iw = fmaxf(__fsub_rn(fminf(rb.w, cb.w), fmaxf(rb.y, cb.y)), 0.0f);
            float inter = __fmul_rn(ih, iw);
            float denom = __fadd_rn(__fsub_rn(__fadd_rn(ra, ca), inter), 1e-8f);
            bool pred = ((double)inter >= M0 * (double)denom);
            word |= ((u64)pred) << c;
        }
        Mb[(size_t)(r0 + lane) * NW + jw] = word;
        asm volatile("" ::: "memory");   // keep LDS rewrite of next iter behind reads
    }
}

// ---------- phase 2: scalar-chain reduce, one wave per batch ----------
// Word-plane PAIRING: lane l owns words 2l (rwA) and 2l+1 (rwB); lanes 0..46
// cover all 94 words. One 16B ulonglong2 per row loads BOTH planes (row
// stride 752B = 47*16 -> aligned), so a chunk is 8 loads (vs 16) and the
// 4-slot ring keeps 32 loads in flight, under the 63-outstanding cap.
__device__ __forceinline__ u64 readlane64(u64 v, int lane) {
    u32 lo = (u32)__builtin_amdgcn_readlane((int)(u32)v, lane);
    u32 hi = (u32)__builtin_amdgcn_readlane((int)(u32)(v >> 32), lane);
    return ((u64)hi << 32) | (u64)lo;
}

#define LOADW(V, chunk) do {                                                  \
    int ck_ = (chunk);                                                        \
    _Pragma("unroll")                                                         \
    for (int r_ = 0; r_ < 8; ++r_) {                                          \
        int row_ = ck_ * 8 + r_; if (row_ >= KSEL) row_ = KSEL - 1;           \
        V[r_] = *(const ulonglong2*)(M + (size_t)row_ * NW + wsel);           \
    }                                                                         \
} while (0)

#define ACCUMW(V, base) do {                                                  \
    _Pragma("unroll")                                                         \
    for (int r_ = 0; r_ < 8; ++r_) {                                          \
        if ((kb >> ((base) + r_)) & 1ull) { rwA |= V[r_].x; rwB |= V[r_].y; } \
    }                                                                         \
} while (0)

#define DIAG(DST, g) do {                                                     \
    int gg_ = (g) < NW ? (g) : NW - 1;                                        \
    int row_ = gg_ * 64 + lane; if (row_ >= KSEL) row_ = KSEL - 1;            \
    DST = M[(size_t)row_ * NW + gg_];                                         \
} while (0)

#define DECIDE(g, DG) do {                                                    \
    u64 rem_ = ((g) & 1) ? readlane64(rwB, (g) >> 1)                          \
                         : readlane64(rwA, (g) >> 1);                         \
    int remaining_ = KSEL - (g) * 64;                                         \
    u64 valid_ = (remaining_ >= 64) ? ~0ull : ((1ull << remaining_) - 1ull);  \
    u64 todo_ = ~rem_ & valid_;                                               \
    kb = 0ull;                                                                \
    while (todo_ && k < PC) {                                                 \
        int i_ = (int)__builtin_ctzll(todo_);                                 \
        kb |= (1ull << i_);                                                   \
        ++k;                                                                  \
        u64 drow_ = readlane64(DG, i_);                                       \
        todo_ &= ~(drow_ | (1ull << i_));                                     \
    }                                                                         \
    if ((kb >> lane) & 1ull) {                                                \
        int rank_ = kprev + (int)__popcll(kb & ((1ull << lane) - 1ull));      \
        keptIdx[rank_] = (u32)((g) * 64 + lane);                              \
    }                                                                         \
    kprev = k;                                                                \
} while (0)

__global__ __launch_bounds__(64) void k_reduce(const u64* __restrict__ mask,
                                               const float4* __restrict__ boxes,
                                               float* __restrict__ outp) {
    __shared__ u32 keptIdx[PC];
    int b = blockIdx.x;
    int lane = threadIdx.x;
    const u64* M = mask + (size_t)b * NR * NW;
    const float4* B4 = boxes + (size_t)b * KSEL;
    int wsel = 2 * lane; if (wsel > 92) wsel = 92;   // lanes >=47 duplicate; never read
    u64 rwA = 0ull, rwB = 0ull;

    ulonglong2 bV[4][8];
    u64 dgA, dgB;
    int k = 0, kprev = 0;
    u64 kb;

    LOADW(bV[0], 0);
    LOADW(bV[1], 1);
    LOADW(bV[2], 2);
    LOADW(bV[3], 3);
    DIAG(dgA, 0);
    DIAG(dgB, 1);

    for (int g = 0; g < NW; g += 2) {
        DECIDE(g, dgA);
        DIAG(dgA, g + 2);
        if (k >= PC) break;
        #pragma unroll
        for (int c = 0; c < 8; ++c) {
            ACCUMW(bV[c & 3], c * 8);
            LOADW(bV[c & 3], g * 8 + c + 4);
        }
        DECIDE(g + 1, dgB);
        DIAG(dgB, g + 3);
        if (k >= PC) break;
        #pragma unroll
        for (int c = 0; c < 8; ++c) {
            ACCUMW(bV[c & 3], c * 8);
            LOADW(bV[c & 3], (g + 1) * 8 + c + 4);
        }
    }
    __syncthreads();

    float4* O = (float4*)outp + (size_t)b * PC;
    for (int t = lane; t < PC; t += 64) {
        float4 v; v.x = 0.0f; v.y = 0.0f; v.z = 0.0f; v.w = 0.0f;
        if (t < k) v = B4[keptIdx[t]];
        O[t] = v;
    }
}

// ---------- fallback serial NMS (used only if ws too small for mask) ----------
__global__ void k_nms(const float4* __restrict__ boxes, float* __restrict__ outp) {
    __shared__ float4 chunk[512];
    __shared__ float4 keptBox[PC];
    __shared__ float  keptArea[PC];
    __shared__ u32    flag[2];
    int b = blockIdx.x;
    int tid = threadIdx.x;
    const float4* B4 = boxes + (size_t)b * KSEL;

    if (tid < 2) flag[tid] = 0u;
    for (int j = tid; j < 512; j += 256) chunk[j] = B4[j];
    __syncthreads();

    int kc = 0;
    for (int i = 0; i < KSEL && kc < PC; ++i) {
        int ci = i & 511;
        if (ci == 0 && i != 0) {
            for (int j = tid; j < 512 && (i + j) < KSEL; j += 256) chunk[j] = B4[i + j];
            __syncthreads();
        }
        float4 cb = chunk[ci];
        float careaV = __fmul_rn(__fsub_rn(cb.z, cb.x), __fsub_rn(cb.w, cb.y));
        bool sup = false;
        for (int t = tid; t < kc; t += 256) {
            float4 kb2 = keptBox[t];
            float ih = fmaxf(__fsub_rn(fminf(cb.z, kb2.z), fmaxf(cb.x, kb2.x)), 0.0f);
            float iw = fmaxf(__fsub_rn(fminf(cb.w, kb2.w), fmaxf(cb.y, kb2.y)), 0.0f);
            float inter = __fmul_rn(ih, iw);
            float denom = __fadd_rn(__fsub_rn(__fadd_rn(careaV, keptArea[t]), inter), 1e-8f);
            if (__fdiv_rn(inter, denom) > NMS_THR) sup = true;
        }
        int p = i & 1;
        if (sup) flag[p] = 1u;
        if (tid == 0) flag[p ^ 1] = 0u;
        __syncthreads();
        if (flag[p] == 0u) {
            if (tid == 0) { keptBox[kc] = cb; keptArea[kc] = careaV; }
            kc++;
        }
        __syncthreads();
    }

    float4* out4 = (float4*)outp + (size_t)b * PC;
    for (int r = tid; r < PC; r += 256) {
        float4 v;
        if (r < kc) v = keptBox[r];
        else { v.x = 0.0f; v.y = 0.0f; v.z = 0.0f; v.w = 0.0f; }
        out4[r] = v;
    }
}

extern "C" void kernel_launch(void* const* d_in, const int* in_sizes, int n_in,
                              void* d_out, int out_size, void* d_ws, size_t ws_size,
                              hipStream_t stream) {
    const float* probs   = (const float*)d_in[0];
    const float* deltas  = (const float*)d_in[1];
    const float* anchors = (const float*)d_in[2];
    float* outp = (float*)d_out;

    u32* ws32 = (u32*)d_ws;
    u32* hist1 = ws32 + HIST1_OFF;
    u32* hist2 = ws32 + HIST2_OFF;
    u32* sel   = ws32 + SEL_OFF;
    u32* candCount = ws32 + CNT_OFF;
    u64* cand   = (u64*)(ws32 + ZERO_WORDS);
    u64* sorted = cand + (size_t)BB * CAP;
    float* boxesF = (float*)(sorted + (size_t)BB * KSEL);
    float4* boxes = (float4*)boxesF;
    u64* mask = (u64*)(boxesF + (size_t)BB * KSEL * 4);

    size_t needed = (size_t)ZERO_WORDS * 4 + (size_t)BB * CAP * 8 + (size_t)BB * KSEL * 8
                  + (size_t)BB * KSEL * 16 + (size_t)BB * NR * NW * 8;

    hipLaunchKernelGGL(k_zero, dim3((ZERO_WORDS + 255) / 256), dim3(256), 0, stream, ws32);
    hipLaunchKernelGGL(k_hist1, dim3(HB, BB), dim3(256), 0, stream, (const float2*)probs, hist1);
    hipLaunchKernelGGL(k_sel1, dim3(BB), dim3(256), 0, stream, hist1, sel);
    hipLaunchKernelGGL(k_hist2, dim3(HB, BB), dim3(256), 0, stream, (const float2*)probs, sel, hist2);
    hipLaunchKernelGGL(k_sel2, dim3(BB), dim3(256), 0, stream, hist2, sel);
    hipLaunchKernelGGL(k_compact, dim3(CB, BB), dim3(256), 0, stream, (const float2*)probs, sel, candCount, cand);
    if (ws_size >= needed) {
        hipLaunchKernelGGL(k_rank, dim3(CAP / 512, BB), dim3(512), 0, stream, cand, candCount, sorted);
        hipLaunchKernelGGL(k_decode, dim3((KSEL + 255) / 256, BB), dim3(256), 0, stream,
                           sorted, (const float4*)anchors, (const float4*)deltas, boxes);
        hipLaunchKernelGGL(k_iou, dim3(NW, COLSPLIT, BB), dim3(256), 0, stream, boxes, mask);
        hipLaunchKernelGGL(k_reduce, dim3(BB), dim3(64), 0, stream, mask, boxes, outp);
    } else {
        hipLaunchKernelGGL(k_sortgather, dim3(BB), dim3(1024), 0, stream,
                           cand, candCount, (const float4*)anchors, (const float4*)deltas, boxes);
        hipLaunchKernelGGL(k_nms, dim3(BB), dim3(256), 0, stream, boxes, outp);
    }
}